// Round 1
// baseline (308.572 us; speedup 1.0000x reference)
//
#include <hip/hip_runtime.h>
#include <hip/hip_bf16.h>

typedef __attribute__((ext_vector_type(8))) short short8v;
typedef __attribute__((ext_vector_type(4))) float f32x4;

__device__ __forceinline__ short f2bf(float f){
  unsigned u = __builtin_bit_cast(unsigned, f);
  u += 0x7fffu + ((u >> 16) & 1u);
  return (short)(u >> 16);
}
__device__ __forceinline__ float bf2f(short s){
  unsigned u = ((unsigned)(unsigned short)s) << 16;
  return __builtin_bit_cast(float, u);
}

// ---------------- concat weights into [384][1152] ----------------
__global__ __launch_bounds__(256) void concat_w_kernel(
    const float* __restrict__ wq, const float* __restrict__ wk, const float* __restrict__ wv,
    const float* __restrict__ wqp, const float* __restrict__ wkp, const float* __restrict__ wvp,
    float* __restrict__ W)
{
  int idx = blockIdx.x*256 + threadIdx.x;
  if (idx >= 384*1152) return;
  int k = idx / 1152, n = idx % 1152;
  float v;
  if      (n < 192) v = wq[k*192 + n];
  else if (n < 384) v = wk[k*192 + (n-192)];
  else if (n < 576) v = wv[k*192 + (n-384)];
  else if (n < 720) v = wqp[k*144 + (n-576)];
  else if (n < 864) v = wkp[k*144 + (n-720)];
  else              v = wvp[k*288 + (n-864)];
  W[idx] = v;
}

// ---------------- bf16 MFMA GEMM: C[M][N] = A[M][K] @ B[K][N] (+bias) ----------------
// Requires: M%128==0, N%128==0, K%32==0. A,B f32 row-major, C f32.
__global__ __launch_bounds__(256) void gemm_kernel(
    const float* __restrict__ A, const float* __restrict__ B,
    float* __restrict__ C, const float* __restrict__ bias,
    int M, int N, int K)
{
  __shared__ short As[128][40];  // row stride 80B (multiple of 16) -> aligned b128 reads
  __shared__ short Bs[128][40];  // stored transposed: Bs[n][k]
  int tid = threadIdx.x;
  int n0 = blockIdx.x * 128, m0 = blockIdx.y * 128;
  int w = tid >> 6, lane = tid & 63;
  int wr = w >> 1, wc = w & 1;
  int lrow = lane & 15, kg = lane >> 4;
  f32x4 acc[4][4] = {};
  for (int k0 = 0; k0 < K; k0 += 32) {
    #pragma unroll
    for (int u = 0; u < 4; ++u) {
      int e = u*1024 + tid*4;
      int r = e >> 5, c = e & 31;
      const float4 f = *(const float4*)(A + (size_t)(m0 + r)*K + k0 + c);
      short4 s4 = make_short4(f2bf(f.x), f2bf(f.y), f2bf(f.z), f2bf(f.w));
      *(short4*)&As[r][c] = s4;
    }
    #pragma unroll
    for (int u = 0; u < 4; ++u) {
      int e = u*1024 + tid*4;
      int kr = e >> 7, nc = e & 127;
      const float4 f = *(const float4*)(B + (size_t)(k0 + kr)*N + n0 + nc);
      Bs[nc+0][kr] = f2bf(f.x); Bs[nc+1][kr] = f2bf(f.y);
      Bs[nc+2][kr] = f2bf(f.z); Bs[nc+3][kr] = f2bf(f.w);
    }
    __syncthreads();
    short8v af[4], bfr[4];
    #pragma unroll
    for (int mi=0; mi<4; ++mi) af[mi]  = *(const short8v*)&As[wr*64 + mi*16 + lrow][kg*8];
    #pragma unroll
    for (int ni=0; ni<4; ++ni) bfr[ni] = *(const short8v*)&Bs[wc*64 + ni*16 + lrow][kg*8];
    #pragma unroll
    for (int mi=0; mi<4; ++mi)
      #pragma unroll
      for (int ni=0; ni<4; ++ni)
        acc[mi][ni] = __builtin_amdgcn_mfma_f32_16x16x32_bf16(af[mi], bfr[ni], acc[mi][ni], 0, 0, 0);
    __syncthreads();
  }
  #pragma unroll
  for (int mi=0; mi<4; ++mi)
    #pragma unroll
    for (int ni=0; ni<4; ++ni) {
      int col = n0 + wc*64 + ni*16 + lrow;
      float bv = bias ? bias[col] : 0.f;
      #pragma unroll
      for (int jj=0; jj<4; ++jj) {
        int row = m0 + wr*64 + mi*16 + kg*4 + jj;
        C[(size_t)row*N + col] = acc[mi][ni][jj] + bv;
      }
    }
}

// ---------------- rigid transforms + transposed layouts ----------------
__global__ __launch_bounds__(256) void transform_kernel(
    const float* __restrict__ P, const float* __restrict__ T,
    float* __restrict__ kT, float* __restrict__ vT, float* __restrict__ qpg,
    float* __restrict__ kpgT, float* __restrict__ vpgT)
{
  int tid = blockIdx.x*256 + threadIdx.x;
  if (tid >= 6144) return;
  int j = tid & 511, h = tid >> 9;
  const float* Tr = T + j*16;
  float R0=Tr[0],R1=Tr[1],R2=Tr[2],t0=Tr[3];
  float R3=Tr[4],R4=Tr[5],R5=Tr[6],t1=Tr[7];
  float R6=Tr[8],R7=Tr[9],R8=Tr[10],t2=Tr[11];
  const float* Pr = P + (size_t)j*1152;
  #pragma unroll
  for (int c=0;c<16;++c){
    kT[(h*16+c)*512 + j] = Pr[192 + h*16 + c];
    vT[(h*16+c)*512 + j] = Pr[384 + h*16 + c];
  }
  #pragma unroll
  for (int p=0;p<4;++p){
    float x=Pr[576+h*12+p*3], y=Pr[576+h*12+p*3+1], zz=Pr[576+h*12+p*3+2];
    qpg[(size_t)j*144 + h*12+p*3+0] = R0*x+R1*y+R2*zz+t0;
    qpg[(size_t)j*144 + h*12+p*3+1] = R3*x+R4*y+R5*zz+t1;
    qpg[(size_t)j*144 + h*12+p*3+2] = R6*x+R7*y+R8*zz+t2;
    x=Pr[720+h*12+p*3]; y=Pr[720+h*12+p*3+1]; zz=Pr[720+h*12+p*3+2];
    kpgT[(h*12+p*3+0)*512 + j] = R0*x+R1*y+R2*zz+t0;
    kpgT[(h*12+p*3+1)*512 + j] = R3*x+R4*y+R5*zz+t1;
    kpgT[(h*12+p*3+2)*512 + j] = R6*x+R7*y+R8*zz+t2;
  }
  #pragma unroll
  for (int p=0;p<8;++p){
    float x=Pr[864+h*24+p*3], y=Pr[864+h*24+p*3+1], zz=Pr[864+h*24+p*3+2];
    vpgT[(h*24+p*3+0)*512 + j] = R0*x+R1*y+R2*zz+t0;
    vpgT[(h*24+p*3+1)*512 + j] = R3*x+R4*y+R5*zz+t1;
    vpgT[(h*24+p*3+2)*512 + j] = R6*x+R7*y+R8*zz+t2;
  }
}

// ---------------- bias: z (262144x128) @ w_b (128x12) -> biasb[i][h][j] ----------------
__global__ __launch_bounds__(256) void bias_kernel(
    const float* __restrict__ z, const float* __restrict__ w_b, float* __restrict__ biasb)
{
  __shared__ short zs[128][132];
  __shared__ float wbs[1536];
  int tid = threadIdx.x;
  size_t r0 = (size_t)blockIdx.x * 128;
  #pragma unroll
  for (int u=0; u<16; ++u) {
    int e = u*1024 + tid*4;
    int r = e >> 7, c = e & 127;
    float4 f = *(const float4*)(z + (r0 + r)*128 + c);
    short4 s4 = make_short4(f2bf(f.x),f2bf(f.y),f2bf(f.z),f2bf(f.w));
    *(short4*)&zs[r][c] = s4;
  }
  for (int u=tid; u<1536; u+=256) wbs[u] = w_b[u];
  __syncthreads();
  int jl = tid & 127, half = tid >> 7;
  float acc[6] = {};
  for (int c=0;c<128;++c){
    float zv = bf2f(zs[jl][c]);
    #pragma unroll
    for (int hh=0; hh<6; ++hh) acc[hh] += zv * wbs[c*12 + half*6 + hh];
  }
  size_t g = r0 + jl;
  int i = (int)(g >> 9), j = (int)(g & 511);
  #pragma unroll
  for (int hh=0; hh<6; ++hh)
    biasb[((size_t)i*12 + half*6 + hh)*512 + j] = acc[hh];
}

// ---------------- per-residue attention ----------------
__global__ __launch_bounds__(512) void attn_kernel(
    const float* __restrict__ P, const float* __restrict__ qpg,
    const float* __restrict__ kT, const float* __restrict__ vT,
    const float* __restrict__ kpgT, const float* __restrict__ vpgT,
    const float* __restrict__ biasb, const float* __restrict__ z,
    const float* __restrict__ T, const float* __restrict__ gamma,
    float* __restrict__ cat)
{
  __shared__ float sc[12][512];
  __shared__ float pairpart[1536];
  __shared__ float qrow[192], qpgrow[144], gsp[12], Ri[9], ti[3];
  __shared__ float obuf[192], opgbuf[288];
  int i = blockIdx.x, tid = threadIdx.x;

  if (tid < 192) qrow[tid] = P[(size_t)i*1152 + tid];
  { int t2 = tid - 192; if (t2 >= 0 && t2 < 144) qpgrow[t2] = qpg[(size_t)i*144 + t2]; }
  { int t3 = tid - 336; if (t3 >= 0 && t3 < 12) { float g = gamma[t3]; gsp[t3] = log1pf(__expf(g)); } }
  { int t4 = tid - 352; if (t4 >= 0 && t4 < 9) Ri[t4] = T[i*16 + (t4/3)*4 + (t4%3)]; }
  { int t5 = tid - 364; if (t5 >= 0 && t5 < 3) ti[t5] = T[i*16 + t5*4 + 3]; }
  for (int u=tid; u<1536; u+=512) pairpart[u] = 0.f;
  __syncthreads();

  // P1: logits
  {
    const int j = tid;
    const float wL = 0.57735026918962576f;
    const float wC = 0.23570226039551584f;
    for (int h=0; h<12; ++h) {
      float dot = 0.f;
      #pragma unroll
      for (int c=0;c<16;++c) dot += qrow[h*16+c] * kT[(h*16+c)*512 + j];
      float d2 = 0.f;
      #pragma unroll
      for (int e=0;e<12;++e){ float d = qpgrow[h*12+e] - kpgT[(h*12+e)*512 + j]; d2 += d*d; }
      float b = biasb[((size_t)i*12 + h)*512 + j];
      sc[h][j] = wL*(dot*0.25f + b - 0.5f*gsp[h]*wC*d2);
    }
  }
  __syncthreads();

  // P2: softmax per head (wave per head)
  {
    int w = tid >> 6, lane = tid & 63;
    for (int r=0; r<2; ++r) {
      int h = w + r*8;
      if (h < 12) {
        float v[8]; float m = -1e30f;
        #pragma unroll
        for (int u=0;u<8;++u){ v[u] = sc[h][lane + u*64]; m = fmaxf(m, v[u]); }
        #pragma unroll
        for (int s=32;s>0;s>>=1) m = fmaxf(m, __shfl_xor(m, s));
        float sum = 0.f;
        #pragma unroll
        for (int u=0;u<8;++u){ v[u] = __expf(v[u]-m); sum += v[u]; }
        #pragma unroll
        for (int s=32;s>0;s>>=1) sum += __shfl_xor(sum, s);
        float rinv = 1.f/sum;
        #pragma unroll
        for (int u=0;u<8;++u) sc[h][lane + u*64] = v[u]*rinv;
      }
    }
  }
  __syncthreads();

  // P3: o (192 dots) and opg (288 dots), one wave per dot
  {
    int w = tid >> 6, lane = tid & 63;
    for (int dd=0; dd<60; ++dd) {
      int d = w*60 + dd;
      const float* base; float* out; int h;
      if (d < 192) { h = d >> 4; base = vT + (size_t)d*512; out = &obuf[d]; }
      else { int e = d-192; h = e/24; base = vpgT + (size_t)e*512; out = &opgbuf[e]; }
      float s = 0.f;
      #pragma unroll
      for (int u=0;u<8;++u){ int jj = lane + u*64; s += sc[h][jj]*base[jj]; }
      #pragma unroll
      for (int t=32;t>0;t>>=1) s += __shfl_xor(s, t);
      if (lane == 0) *out = s;
    }
  }
  __syncthreads();

  // P4: o_pair = a @ z[i]
  {
    int zc = tid & 127, jq = tid >> 7;
    float acc[12] = {};
    const float* zrow = z + ((size_t)i*512 + (size_t)jq*128)*128 + zc;
    for (int jj=0; jj<128; ++jj) {
      float zv = zrow[(size_t)jj*128];
      int j = jq*128 + jj;
      #pragma unroll
      for (int h=0;h<12;++h) acc[h] += sc[h][j]*zv;
    }
    #pragma unroll
    for (int h=0;h<12;++h) atomicAdd(&pairpart[h*128 + zc], acc[h]);
  }
  __syncthreads();

  // P5: finalize cat row
  float* crow = cat + (size_t)i*2112;
  if (tid < 192) crow[tid] = obuf[tid];
  else if (tid < 288) {
    int idx = tid - 192;
    float d0 = opgbuf[idx*3+0]-ti[0], d1 = opgbuf[idx*3+1]-ti[1], d2v = opgbuf[idx*3+2]-ti[2];
    float o0 = Ri[0]*d0 + Ri[3]*d1 + Ri[6]*d2v;
    float o1 = Ri[1]*d0 + Ri[4]*d1 + Ri[7]*d2v;
    float o2 = Ri[2]*d0 + Ri[5]*d1 + Ri[8]*d2v;
    crow[192+idx*3+0] = o0; crow[192+idx*3+1] = o1; crow[192+idx*3+2] = o2;
    crow[480+idx] = sqrtf(o0*o0 + o1*o1 + o2*o2 + 1e-8f);
  }
  for (int u=tid; u<1536; u+=512) crow[576+u] = pairpart[u];
}

// ---------------- launch ----------------
extern "C" void kernel_launch(void* const* d_in, const int* in_sizes, int n_in,
                              void* d_out, int out_size, void* d_ws, size_t ws_size,
                              hipStream_t stream) {
  const float* s     = (const float*)d_in[0];
  const float* z     = (const float*)d_in[1];
  const float* T     = (const float*)d_in[2];
  const float* w_q   = (const float*)d_in[3];
  const float* w_k   = (const float*)d_in[4];
  const float* w_v   = (const float*)d_in[5];
  const float* w_qp  = (const float*)d_in[6];
  const float* w_kp  = (const float*)d_in[7];
  const float* w_vp  = (const float*)d_in[8];
  const float* w_b   = (const float*)d_in[9];
  const float* gamma = (const float*)d_in[10];
  const float* w_out = (const float*)d_in[11];
  const float* b_out = (const float*)d_in[12];

  float* ws = (float*)d_ws;
  float* W     = ws;             // 442368
  float* P     = ws + 442368;    // 589824
  float* kT    = ws + 1032192;   // 98304
  float* vT    = ws + 1130496;   // 98304
  float* qpg   = ws + 1228800;   // 73728
  float* kpgT  = ws + 1302528;   // 73728
  float* vpgT  = ws + 1376256;   // 147456
  float* biasb = ws + 1523712;   // 3145728
  float* cat   = ws + 4669440;   // 1081344

  concat_w_kernel<<<1728, 256, 0, stream>>>(w_q, w_k, w_v, w_qp, w_kp, w_vp, W);
  gemm_kernel<<<dim3(9,4), 256, 0, stream>>>(s, W, P, nullptr, 512, 1152, 384);
  transform_kernel<<<24, 256, 0, stream>>>(P, T, kT, vT, qpg, kpgT, vpgT);
  bias_kernel<<<2048, 256, 0, stream>>>(z, w_b, biasb);
  attn_kernel<<<512, 512, 0, stream>>>(P, qpg, kT, vT, kpgT, vpgT, biasb, z, T, gamma, cat);
  gemm_kernel<<<dim3(3,4), 256, 0, stream>>>(cat, w_out, (float*)d_out, b_out, 512, 384, 2112);
}

// Round 2
// 210.549 us; speedup vs baseline: 1.4656x; 1.4656x over previous
//
#include <hip/hip_runtime.h>
#include <hip/hip_bf16.h>

typedef __attribute__((ext_vector_type(8))) short short8v;
typedef __attribute__((ext_vector_type(4))) float f32x4;

__device__ __forceinline__ short f2bf(float f){
  unsigned u = __builtin_bit_cast(unsigned, f);
  u += 0x7fffu + ((u >> 16) & 1u);
  return (short)(u >> 16);
}
__device__ __forceinline__ float bf2f(short s){
  unsigned u = ((unsigned)(unsigned short)s) << 16;
  return __builtin_bit_cast(float, u);
}

__device__ __forceinline__ void gload16(const short* g, short* l){
  __builtin_amdgcn_global_load_lds(
    (const __attribute__((address_space(1))) unsigned int*)g,
    (__attribute__((address_space(3))) unsigned int*)l,
    16, 0, 0);
}

// ---------------- prep: s->bf16, W^T bf16 concat, w_out^T bf16 ----------------
__global__ __launch_bounds__(256) void prep_kernel(
    const float* __restrict__ s,
    const float* __restrict__ wq, const float* __restrict__ wk, const float* __restrict__ wv,
    const float* __restrict__ wqp, const float* __restrict__ wkp, const float* __restrict__ wvp,
    const float* __restrict__ w_out,
    short* __restrict__ s_bf, short* __restrict__ WT, short* __restrict__ w_outT)
{
  int b = blockIdx.x;
  if (b < 192) {
    int gid = b*256 + threadIdx.x;             // 49152 threads x 4 elems = 196608
    float4 f = *(const float4*)(s + (size_t)gid*4);
    short4 o = make_short4(f2bf(f.x), f2bf(f.y), f2bf(f.z), f2bf(f.w));
    *(short4*)(s_bf + (size_t)gid*4) = o;
  } else if (b < 192 + 1728) {
    int idx = (b-192)*256 + threadIdx.x;       // 442368 = 1152*384
    int n = idx / 384, k = idx % 384;
    const float* src; int col, stride;
    if      (n < 192) { src = wq;  col = n;       stride = 192; }
    else if (n < 384) { src = wk;  col = n-192;   stride = 192; }
    else if (n < 576) { src = wv;  col = n-384;   stride = 192; }
    else if (n < 720) { src = wqp; col = n-576;   stride = 144; }
    else if (n < 864) { src = wkp; col = n-720;   stride = 144; }
    else              { src = wvp; col = n-864;   stride = 288; }
    WT[idx] = f2bf(src[(size_t)k*stride + col]);
  } else {
    int idx = (b-192-1728)*256 + threadIdx.x;  // 811008 = 384*2112
    int n = idx / 2112, k = idx % 2112;
    w_outT[idx] = f2bf(w_out[(size_t)k*384 + n]);
  }
}

// ---------------- bf16 MFMA GEMM: C[M][N] = A[M][K] @ BT[N][K]^T (+bias) ----------------
// A [M][K] bf16 row-major, BT [N][K] bf16 row-major, C f32. M%128==0, N%128==0, K%32==0.
// Double-buffered global_load_lds staging, counted vmcnt, raw barriers.
__global__ __launch_bounds__(256) void gemm_bf16_kernel(
    const short* __restrict__ A, const short* __restrict__ BT,
    float* __restrict__ C, const float* __restrict__ bias,
    int M, int N, int K)
{
  __shared__ __align__(16) short As[2][4096];   // [128 rows][32 k] per buffer
  __shared__ __align__(16) short Bs[2][4096];
  int tid = threadIdx.x;
  int n0 = blockIdx.x*128, m0 = blockIdx.y*128;
  int w = tid >> 6, lane = tid & 63;
  int wr = w >> 1, wc = w & 1;
  int lrow = lane & 15, kg = lane >> 4;
  int nt = K >> 5;
  f32x4 acc[4][4] = {};

  const short* Abase = A  + (size_t)m0*K;
  const short* Bbase = BT + (size_t)n0*K;
  int sr = tid >> 2, sc = (tid & 3)*8;

  auto stage = [&](int b, int k0){
    const short* Ab = Abase + k0;
    const short* Bb = Bbase + k0;
    gload16(Ab + (size_t)sr*K + sc,      &As[b][tid*8]);
    gload16(Bb + (size_t)sr*K + sc,      &Bs[b][tid*8]);
    gload16(Ab + (size_t)(sr+64)*K + sc, &As[b][2048 + tid*8]);
    gload16(Bb + (size_t)(sr+64)*K + sc, &Bs[b][2048 + tid*8]);
  };

  stage(0, 0);
  for (int kt = 0; kt < nt; ++kt){
    int cb = kt & 1;
    if (kt + 1 < nt){
      stage(cb ^ 1, (kt+1) << 5);
      asm volatile("s_waitcnt vmcnt(4)" ::: "memory");
    } else {
      asm volatile("s_waitcnt vmcnt(0)" ::: "memory");
    }
    __builtin_amdgcn_s_barrier();
    short8v af[4], bfr[4];
    #pragma unroll
    for (int mi=0; mi<4; ++mi)
      af[mi]  = *(const short8v*)&As[cb][(wr*64 + mi*16 + lrow)*32 + kg*8];
    #pragma unroll
    for (int ni=0; ni<4; ++ni)
      bfr[ni] = *(const short8v*)&Bs[cb][(wc*64 + ni*16 + lrow)*32 + kg*8];
    #pragma unroll
    for (int mi=0; mi<4; ++mi)
      #pragma unroll
      for (int ni=0; ni<4; ++ni)
        acc[mi][ni] = __builtin_amdgcn_mfma_f32_16x16x32_bf16(af[mi], bfr[ni], acc[mi][ni], 0, 0, 0);
    __builtin_amdgcn_s_barrier();
  }

  #pragma unroll
  for (int mi=0; mi<4; ++mi)
    #pragma unroll
    for (int ni=0; ni<4; ++ni) {
      int col = n0 + wc*64 + ni*16 + lrow;
      float bv = bias ? bias[col] : 0.f;
      #pragma unroll
      for (int jj=0; jj<4; ++jj) {
        int row = m0 + wr*64 + mi*16 + kg*4 + jj;
        C[(size_t)row*N + col] = acc[mi][ni][jj] + bv;
      }
    }
}

// ---------------- rigid transforms + transposed layouts ----------------
__global__ __launch_bounds__(256) void transform_kernel(
    const float* __restrict__ P, const float* __restrict__ T,
    float* __restrict__ kT, float* __restrict__ vT, float* __restrict__ qpg,
    float* __restrict__ kpgT, float* __restrict__ vpgT)
{
  int tid = blockIdx.x*256 + threadIdx.x;
  if (tid >= 6144) return;
  int j = tid & 511, h = tid >> 9;
  const float* Tr = T + j*16;
  float R0=Tr[0],R1=Tr[1],R2=Tr[2],t0=Tr[3];
  float R3=Tr[4],R4=Tr[5],R5=Tr[6],t1=Tr[7];
  float R6=Tr[8],R7=Tr[9],R8=Tr[10],t2=Tr[11];
  const float* Pr = P + (size_t)j*1152;
  #pragma unroll
  for (int c=0;c<16;++c){
    kT[(h*16+c)*512 + j] = Pr[192 + h*16 + c];
    vT[(h*16+c)*512 + j] = Pr[384 + h*16 + c];
  }
  #pragma unroll
  for (int p=0;p<4;++p){
    float x=Pr[576+h*12+p*3], y=Pr[576+h*12+p*3+1], zz=Pr[576+h*12+p*3+2];
    qpg[(size_t)j*144 + h*12+p*3+0] = R0*x+R1*y+R2*zz+t0;
    qpg[(size_t)j*144 + h*12+p*3+1] = R3*x+R4*y+R5*zz+t1;
    qpg[(size_t)j*144 + h*12+p*3+2] = R6*x+R7*y+R8*zz+t2;
    x=Pr[720+h*12+p*3]; y=Pr[720+h*12+p*3+1]; zz=Pr[720+h*12+p*3+2];
    kpgT[(h*12+p*3+0)*512 + j] = R0*x+R1*y+R2*zz+t0;
    kpgT[(h*12+p*3+1)*512 + j] = R3*x+R4*y+R5*zz+t1;
    kpgT[(h*12+p*3+2)*512 + j] = R6*x+R7*y+R8*zz+t2;
  }
  #pragma unroll
  for (int p=0;p<8;++p){
    float x=Pr[864+h*24+p*3], y=Pr[864+h*24+p*3+1], zz=Pr[864+h*24+p*3+2];
    vpgT[(h*24+p*3+0)*512 + j] = R0*x+R1*y+R2*zz+t0;
    vpgT[(h*24+p*3+1)*512 + j] = R3*x+R4*y+R5*zz+t1;
    vpgT[(h*24+p*3+2)*512 + j] = R6*x+R7*y+R8*zz+t2;
  }
}

// ---------------- bias: z (262144x128) @ w_b (128x12) -> biasb[i][h][j] ----------------
__global__ __launch_bounds__(256) void bias_kernel(
    const float* __restrict__ z, const float* __restrict__ w_b, float* __restrict__ biasb)
{
  __shared__ short zs[128][132];
  __shared__ float wbs[1536];
  int tid = threadIdx.x;
  size_t r0 = (size_t)blockIdx.x * 128;
  #pragma unroll
  for (int u=0; u<16; ++u) {
    int e = u*1024 + tid*4;
    int r = e >> 7, c = e & 127;
    float4 f = *(const float4*)(z + (r0 + r)*128 + c);
    short4 s4 = make_short4(f2bf(f.x),f2bf(f.y),f2bf(f.z),f2bf(f.w));
    *(short4*)&zs[r][c] = s4;
  }
  for (int u=tid; u<1536; u+=256) wbs[u] = w_b[u];
  __syncthreads();
  int jl = tid & 127, half = tid >> 7;
  float acc[6] = {};
  for (int c=0;c<128;++c){
    float zv = bf2f(zs[jl][c]);
    #pragma unroll
    for (int hh=0; hh<6; ++hh) acc[hh] += zv * wbs[c*12 + half*6 + hh];
  }
  size_t g = r0 + jl;
  int i = (int)(g >> 9), j = (int)(g & 511);
  #pragma unroll
  for (int hh=0; hh<6; ++hh)
    biasb[((size_t)i*12 + half*6 + hh)*512 + j] = acc[hh];
}

// ---------------- per-residue attention ----------------
__global__ __launch_bounds__(512) void attn_kernel(
    const float* __restrict__ P, const float* __restrict__ qpg,
    const float* __restrict__ kT, const float* __restrict__ vT,
    const float* __restrict__ kpgT, const float* __restrict__ vpgT,
    const float* __restrict__ biasb, const float* __restrict__ z,
    const float* __restrict__ T, const float* __restrict__ gamma,
    short* __restrict__ cat)
{
  __shared__ float sc[12][512];
  __shared__ float pairpart[1536];
  __shared__ float qrow[192], qpgrow[144], gsp[12], Ri[9], ti[3];
  __shared__ float obuf[192], opgbuf[288];
  int i = blockIdx.x, tid = threadIdx.x;

  if (tid < 192) qrow[tid] = P[(size_t)i*1152 + tid];
  { int t2 = tid - 192; if (t2 >= 0 && t2 < 144) qpgrow[t2] = qpg[(size_t)i*144 + t2]; }
  { int t3 = tid - 336; if (t3 >= 0 && t3 < 12) { float g = gamma[t3]; gsp[t3] = log1pf(__expf(g)); } }
  { int t4 = tid - 352; if (t4 >= 0 && t4 < 9) Ri[t4] = T[i*16 + (t4/3)*4 + (t4%3)]; }
  { int t5 = tid - 364; if (t5 >= 0 && t5 < 3) ti[t5] = T[i*16 + t5*4 + 3]; }
  for (int u=tid; u<1536; u+=512) pairpart[u] = 0.f;
  __syncthreads();

  // P1: logits
  {
    const int j = tid;
    const float wL = 0.57735026918962576f;
    const float wC = 0.23570226039551584f;
    for (int h=0; h<12; ++h) {
      float dot = 0.f;
      #pragma unroll
      for (int c=0;c<16;++c) dot += qrow[h*16+c] * kT[(h*16+c)*512 + j];
      float d2 = 0.f;
      #pragma unroll
      for (int e=0;e<12;++e){ float d = qpgrow[h*12+e] - kpgT[(h*12+e)*512 + j]; d2 += d*d; }
      float b = biasb[((size_t)i*12 + h)*512 + j];
      sc[h][j] = wL*(dot*0.25f + b - 0.5f*gsp[h]*wC*d2);
    }
  }
  __syncthreads();

  // P2: softmax per head (wave per head)
  {
    int w = tid >> 6, lane = tid & 63;
    for (int r=0; r<2; ++r) {
      int h = w + r*8;
      if (h < 12) {
        float v[8]; float m = -1e30f;
        #pragma unroll
        for (int u=0;u<8;++u){ v[u] = sc[h][lane + u*64]; m = fmaxf(m, v[u]); }
        #pragma unroll
        for (int s=32;s>0;s>>=1) m = fmaxf(m, __shfl_xor(m, s));
        float sum = 0.f;
        #pragma unroll
        for (int u=0;u<8;++u){ v[u] = __expf(v[u]-m); sum += v[u]; }
        #pragma unroll
        for (int s=32;s>0;s>>=1) sum += __shfl_xor(sum, s);
        float rinv = 1.f/sum;
        #pragma unroll
        for (int u=0;u<8;++u) sc[h][lane + u*64] = v[u]*rinv;
      }
    }
  }
  __syncthreads();

  // P3: o (192 dots) and opg (288 dots), one wave per dot
  {
    int w = tid >> 6, lane = tid & 63;
    for (int dd=0; dd<60; ++dd) {
      int d = w*60 + dd;
      const float* base; float* out; int h;
      if (d < 192) { h = d >> 4; base = vT + (size_t)d*512; out = &obuf[d]; }
      else { int e = d-192; h = e/24; base = vpgT + (size_t)e*512; out = &opgbuf[e]; }
      float s = 0.f;
      #pragma unroll
      for (int u=0;u<8;++u){ int jj = lane + u*64; s += sc[h][jj]*base[jj]; }
      #pragma unroll
      for (int t=32;t>0;t>>=1) s += __shfl_xor(s, t);
      if (lane == 0) *out = s;
    }
  }
  __syncthreads();

  // P4: o_pair = a @ z[i]
  {
    int zc = tid & 127, jq = tid >> 7;
    float acc[12] = {};
    const float* zrow = z + ((size_t)i*512 + (size_t)jq*128)*128 + zc;
    for (int jj=0; jj<128; ++jj) {
      float zv = zrow[(size_t)jj*128];
      int j = jq*128 + jj;
      #pragma unroll
      for (int h=0;h<12;++h) acc[h] += sc[h][j]*zv;
    }
    #pragma unroll
    for (int h=0;h<12;++h) atomicAdd(&pairpart[h*128 + zc], acc[h]);
  }
  __syncthreads();

  // P5: finalize cat row (bf16)
  short* crow = cat + (size_t)i*2112;
  if (tid < 192) crow[tid] = f2bf(obuf[tid]);
  else if (tid < 288) {
    int idx = tid - 192;
    float d0 = opgbuf[idx*3+0]-ti[0], d1 = opgbuf[idx*3+1]-ti[1], d2v = opgbuf[idx*3+2]-ti[2];
    float o0 = Ri[0]*d0 + Ri[3]*d1 + Ri[6]*d2v;
    float o1 = Ri[1]*d0 + Ri[4]*d1 + Ri[7]*d2v;
    float o2 = Ri[2]*d0 + Ri[5]*d1 + Ri[8]*d2v;
    crow[192+idx*3+0] = f2bf(o0); crow[192+idx*3+1] = f2bf(o1); crow[192+idx*3+2] = f2bf(o2);
    crow[480+idx] = f2bf(sqrtf(o0*o0 + o1*o1 + o2*o2 + 1e-8f));
  }
  for (int u=tid; u<1536; u+=512) crow[576+u] = f2bf(pairpart[u]);
}

// ---------------- launch ----------------
extern "C" void kernel_launch(void* const* d_in, const int* in_sizes, int n_in,
                              void* d_out, int out_size, void* d_ws, size_t ws_size,
                              hipStream_t stream) {
  const float* s     = (const float*)d_in[0];
  const float* z     = (const float*)d_in[1];
  const float* T     = (const float*)d_in[2];
  const float* w_q   = (const float*)d_in[3];
  const float* w_k   = (const float*)d_in[4];
  const float* w_v   = (const float*)d_in[5];
  const float* w_qp  = (const float*)d_in[6];
  const float* w_kp  = (const float*)d_in[7];
  const float* w_vp  = (const float*)d_in[8];
  const float* w_b   = (const float*)d_in[9];
  const float* gamma = (const float*)d_in[10];
  const float* w_out = (const float*)d_in[11];
  const float* b_out = (const float*)d_in[12];

  float* ws = (float*)d_ws;
  float* P      = ws;               // 589824
  float* kT     = ws + 589824;      // 98304
  float* vT     = ws + 688128;      // 98304
  float* qpg    = ws + 786432;      // 73728
  float* kpgT   = ws + 860160;      // 73728
  float* vpgT   = ws + 933888;      // 147456
  float* biasb  = ws + 1081344;     // 3145728
  short* s_bf   = (short*)(ws + 4227072);  // 196608 shorts
  short* WT     = (short*)(ws + 4325376);  // 442368 shorts
  short* w_outT = (short*)(ws + 4546560);  // 811008 shorts
  short* cat    = (short*)(ws + 4952064);  // 1081344 shorts

  prep_kernel<<<5088, 256, 0, stream>>>(s, w_q, w_k, w_v, w_qp, w_kp, w_vp, w_out,
                                        s_bf, WT, w_outT);
  gemm_bf16_kernel<<<dim3(9,4), 256, 0, stream>>>(s_bf, WT, P, nullptr, 512, 1152, 384);
  transform_kernel<<<24, 256, 0, stream>>>(P, T, kT, vT, qpg, kpgT, vpgT);
  bias_kernel<<<2048, 256, 0, stream>>>(z, w_b, biasb);
  attn_kernel<<<512, 512, 0, stream>>>(P, qpg, kT, vT, kpgT, vpgT, biasb, z, T, gamma, cat);
  gemm_bf16_kernel<<<dim3(3,4), 256, 0, stream>>>(cat, w_outT, (float*)d_out, b_out, 512, 384, 2112);
}

// Round 3
// 203.440 us; speedup vs baseline: 1.5168x; 1.0349x over previous
//
#include <hip/hip_runtime.h>
#include <hip/hip_bf16.h>

typedef __attribute__((ext_vector_type(8))) short short8v;
typedef __attribute__((ext_vector_type(4))) float f32x4;

__device__ __forceinline__ short f2bf(float f){
  unsigned u = __builtin_bit_cast(unsigned, f);
  u += 0x7fffu + ((u >> 16) & 1u);
  return (short)(u >> 16);
}
__device__ __forceinline__ float bf2f(unsigned short s){
  unsigned u = ((unsigned)s) << 16;
  return __builtin_bit_cast(float, u);
}

__device__ __forceinline__ void gload16(const short* g, short* l){
  __builtin_amdgcn_global_load_lds(
    (const __attribute__((address_space(1))) unsigned int*)g,
    (__attribute__((address_space(3))) unsigned int*)l,
    16, 0, 0);
}

// ---------------- cast s -> bf16 ----------------
__global__ __launch_bounds__(256) void cast_s_kernel(
    const float* __restrict__ s, short* __restrict__ s_bf)
{
  int gid = blockIdx.x*256 + threadIdx.x;          // 49152 x float4
  float4 f = *(const float4*)(s + (size_t)gid*4);
  short4 o = make_short4(f2bf(f.x), f2bf(f.y), f2bf(f.z), f2bf(f.w));
  *(short4*)(s_bf + (size_t)gid*4) = o;
}

// ---------------- transpose 6 projection weights into WT[1152][384] bf16 ----------------
__global__ __launch_bounds__(256) void transpose_w_kernel(
    const float* __restrict__ wq, const float* __restrict__ wk, const float* __restrict__ wv,
    const float* __restrict__ wqp, const float* __restrict__ wkp, const float* __restrict__ wvp,
    short* __restrict__ WT)
{
  __shared__ float t[64][65];
  int src = blockIdx.z;
  const float* in; int N; int rowoff;
  switch (src) {
    case 0: in = wq;  N = 192; rowoff = 0;   break;
    case 1: in = wk;  N = 192; rowoff = 192; break;
    case 2: in = wv;  N = 192; rowoff = 384; break;
    case 3: in = wqp; N = 144; rowoff = 576; break;
    case 4: in = wkp; N = 144; rowoff = 720; break;
    default:in = wvp; N = 288; rowoff = 864; break;
  }
  int n0 = blockIdx.x*64;
  if (n0 >= N) return;
  int k0 = blockIdx.y*64;                           // K=384, always full
  int lx = threadIdx.x & 15, ly = threadIdx.x >> 4;
  #pragma unroll
  for (int p=0;p<4;++p){
    int r = ly + p*16, c = lx*4;
    float v0=0.f,v1=0.f,v2=0.f,v3=0.f;
    if (n0 + c + 3 < N) {
      float4 v = *(const float4*)(in + (size_t)(k0+r)*N + n0 + c);
      v0=v.x; v1=v.y; v2=v.z; v3=v.w;
    } else {
      if (n0+c+0 < N) v0 = in[(size_t)(k0+r)*N + n0+c+0];
      if (n0+c+1 < N) v1 = in[(size_t)(k0+r)*N + n0+c+1];
      if (n0+c+2 < N) v2 = in[(size_t)(k0+r)*N + n0+c+2];
      if (n0+c+3 < N) v3 = in[(size_t)(k0+r)*N + n0+c+3];
    }
    t[c+0][r]=v0; t[c+1][r]=v1; t[c+2][r]=v2; t[c+3][r]=v3;
  }
  __syncthreads();
  #pragma unroll
  for (int p=0;p<4;++p){
    int nr = ly + p*16, kc = lx*4;
    if (n0 + nr < N) {
      short4 o = make_short4(f2bf(t[nr][kc]), f2bf(t[nr][kc+1]),
                             f2bf(t[nr][kc+2]), f2bf(t[nr][kc+3]));
      *(short4*)(WT + (size_t)(rowoff+n0+nr)*384 + k0 + kc) = o;
    }
  }
}

// ---------------- transpose w_out [2112][384] -> w_outT [384][2112] bf16 ----------------
__global__ __launch_bounds__(256) void transpose_wout_kernel(
    const float* __restrict__ in, short* __restrict__ out)
{
  __shared__ float t[64][65];
  int n0 = blockIdx.x*64;     // over 384
  int k0 = blockIdx.y*64;     // over 2112
  int lx = threadIdx.x & 15, ly = threadIdx.x >> 4;
  #pragma unroll
  for (int p=0;p<4;++p){
    int r = ly + p*16, c = lx*4;
    float4 v = *(const float4*)(in + (size_t)(k0+r)*384 + n0 + c);
    t[c+0][r]=v.x; t[c+1][r]=v.y; t[c+2][r]=v.z; t[c+3][r]=v.w;
  }
  __syncthreads();
  #pragma unroll
  for (int p=0;p<4;++p){
    int nr = ly + p*16, kc = lx*4;
    short4 o = make_short4(f2bf(t[nr][kc]), f2bf(t[nr][kc+1]),
                           f2bf(t[nr][kc+2]), f2bf(t[nr][kc+3]));
    *(short4*)(out + (size_t)(n0+nr)*2112 + k0 + kc) = o;
  }
}

// ---------------- bf16 MFMA GEMM: C[M][N] = A[M][K] @ BT[N][K]^T (+bias) ----------------
__global__ __launch_bounds__(256) void gemm_bf16_kernel(
    const short* __restrict__ A, const short* __restrict__ BT,
    float* __restrict__ C, const float* __restrict__ bias,
    int M, int N, int K)
{
  __shared__ __align__(16) short As[2][4096];
  __shared__ __align__(16) short Bs[2][4096];
  int tid = threadIdx.x;
  int n0 = blockIdx.x*128, m0 = blockIdx.y*128;
  int w = tid >> 6, lane = tid & 63;
  int wr = w >> 1, wc = w & 1;
  int lrow = lane & 15, kg = lane >> 4;
  int nt = K >> 5;
  f32x4 acc[4][4] = {};

  const short* Abase = A  + (size_t)m0*K;
  const short* Bbase = BT + (size_t)n0*K;
  int sr = tid >> 2, scc = (tid & 3)*8;

  auto stage = [&](int b, int k0){
    const short* Ab = Abase + k0;
    const short* Bb = Bbase + k0;
    gload16(Ab + (size_t)sr*K + scc,      &As[b][tid*8]);
    gload16(Bb + (size_t)sr*K + scc,      &Bs[b][tid*8]);
    gload16(Ab + (size_t)(sr+64)*K + scc, &As[b][2048 + tid*8]);
    gload16(Bb + (size_t)(sr+64)*K + scc, &Bs[b][2048 + tid*8]);
  };

  stage(0, 0);
  for (int kt = 0; kt < nt; ++kt){
    int cb = kt & 1;
    if (kt + 1 < nt){
      stage(cb ^ 1, (kt+1) << 5);
      asm volatile("s_waitcnt vmcnt(4)" ::: "memory");
    } else {
      asm volatile("s_waitcnt vmcnt(0)" ::: "memory");
    }
    __builtin_amdgcn_s_barrier();
    short8v af[4], bfr[4];
    #pragma unroll
    for (int mi=0; mi<4; ++mi)
      af[mi]  = *(const short8v*)&As[cb][(wr*64 + mi*16 + lrow)*32 + kg*8];
    #pragma unroll
    for (int ni=0; ni<4; ++ni)
      bfr[ni] = *(const short8v*)&Bs[cb][(wc*64 + ni*16 + lrow)*32 + kg*8];
    #pragma unroll
    for (int mi=0; mi<4; ++mi)
      #pragma unroll
      for (int ni=0; ni<4; ++ni)
        acc[mi][ni] = __builtin_amdgcn_mfma_f32_16x16x32_bf16(af[mi], bfr[ni], acc[mi][ni], 0, 0, 0);
    __builtin_amdgcn_s_barrier();
  }

  #pragma unroll
  for (int mi=0; mi<4; ++mi)
    #pragma unroll
    for (int ni=0; ni<4; ++ni) {
      int col = n0 + wc*64 + ni*16 + lrow;
      float bv = bias ? bias[col] : 0.f;
      #pragma unroll
      for (int jj=0; jj<4; ++jj) {
        int row = m0 + wr*64 + mi*16 + kg*4 + jj;
        C[(size_t)row*N + col] = acc[mi][ni][jj] + bv;
      }
    }
}

// ---------------- transform: P -> kT, kpgT, qpg, vcatT (LDS-staged, coalesced) ----------------
__global__ __launch_bounds__(256) void transform_kernel(
    const float* __restrict__ P, const float* __restrict__ T,
    float* __restrict__ kT, float* __restrict__ kpgT,
    float* __restrict__ qpg, unsigned short* __restrict__ vcatT)
{
  __shared__ float Ps[8][1160];   // pad 8 -> 2-way banks max
  __shared__ float Ts[8][12];     // R row-major (9) + t (3)
  int tid = threadIdx.x;
  int j0 = blockIdx.x*8;
  for (int u = tid; u < 8*288; u += 256) {
    int r = u / 288, c4 = u % 288;
    *(float4*)&Ps[r][c4*4] = *(const float4*)(P + (size_t)(j0+r)*1152 + c4*4);
  }
  if (tid < 96) {
    int r = tid / 12, e = tid % 12;
    Ts[r][e] = (e < 9) ? T[(j0+r)*16 + (e/3)*4 + (e%3)]
                       : T[(j0+r)*16 + (e-9)*4 + 3];
  }
  __syncthreads();
  // kT[192][512]
  for (int u = tid; u < 1536; u += 256) {
    int row = u >> 3, jl = u & 7;
    kT[(size_t)row*512 + j0 + jl] = Ps[jl][192 + row];
  }
  // kpgT[144][512] (rotated kp)
  for (int u = tid; u < 1152; u += 256) {
    int e = u >> 3, jl = u & 7;
    int x = e % 3, hp = e / 3;
    const float* R = &Ts[jl][0];
    float kx = Ps[jl][720+hp*3], ky = Ps[jl][720+hp*3+1], kz = Ps[jl][720+hp*3+2];
    kpgT[(size_t)e*512 + j0 + jl] = R[x*3]*kx + R[x*3+1]*ky + R[x*3+2]*kz + Ts[jl][9+x];
  }
  // qpg[512][144] (rotated qp)
  for (int u = tid; u < 1152; u += 256) {
    int jl = u / 144, e = u % 144;
    int x = e % 3, hp = e / 3;
    const float* R = &Ts[jl][0];
    float qx = Ps[jl][576+hp*3], qy = Ps[jl][576+hp*3+1], qz = Ps[jl][576+hp*3+2];
    qpg[(size_t)(j0+jl)*144 + e] = R[x*3]*qx + R[x*3+1]*qy + R[x*3+2]*qz + Ts[jl][9+x];
  }
  // vcatT[480][512] bf16: rows 0..191 = v, rows 192..479 = rotated vp
  for (int u = tid; u < 3840; u += 256) {
    int d = u >> 3, jl = u & 7;
    float val;
    if (d < 192) val = Ps[jl][384 + d];
    else {
      int e = d - 192;
      int x = e % 3, hp = e / 3;
      const float* R = &Ts[jl][0];
      float vx = Ps[jl][864+hp*3], vy = Ps[jl][864+hp*3+1], vz = Ps[jl][864+hp*3+2];
      val = R[x*3]*vx + R[x*3+1]*vy + R[x*3+2]*vz + Ts[jl][9+x];
    }
    vcatT[(size_t)d*512 + j0 + jl] = (unsigned short)f2bf(val);
  }
}

// ---------------- zpass: biasb[i][h][j] = wL * (z @ w_b), skinny MFMA GEMM ----------------
__global__ __launch_bounds__(256) void zpass_kernel(
    const float* __restrict__ z, const float* __restrict__ w_b,
    float* __restrict__ biasb)
{
  __shared__ float wbs[1536];
  int tid = threadIdx.x;
  for (int u = tid; u < 1536; u += 256) wbs[u] = w_b[u];
  __syncthreads();
  int w = tid >> 6, lane = tid & 63;
  int col = lane & 15, kg = lane >> 4;
  size_t r0 = (size_t)blockIdx.x*64 + (size_t)w*16;
  const float* zr = z + (r0 + col)*128;
  const float wL = 0.57735026918962576f;
  short8v bfrag[4];
  #pragma unroll
  for (int ks=0; ks<4; ++ks)
    #pragma unroll
    for (int e=0; e<8; ++e){
      int k = ks*32 + kg*8 + e;
      float v = (col < 12) ? wbs[k*12 + col]*wL : 0.f;
      bfrag[ks][e] = f2bf(v);
    }
  f32x4 acc = {0.f,0.f,0.f,0.f};
  #pragma unroll
  for (int ks=0; ks<4; ++ks){
    int c0 = ks*32 + kg*8;
    float4 z0 = *(const float4*)(zr + c0);
    float4 z1 = *(const float4*)(zr + c0 + 4);
    short8v af;
    af[0]=f2bf(z0.x); af[1]=f2bf(z0.y); af[2]=f2bf(z0.z); af[3]=f2bf(z0.w);
    af[4]=f2bf(z1.x); af[5]=f2bf(z1.y); af[6]=f2bf(z1.z); af[7]=f2bf(z1.w);
    acc = __builtin_amdgcn_mfma_f32_16x16x32_bf16(af, bfrag[ks], acc, 0, 0, 0);
  }
  if (col < 12) {
    #pragma unroll
    for (int r=0; r<4; ++r){
      size_t g = r0 + kg*4 + r;
      int ii = (int)(g >> 9), jj = (int)(g & 511);
      biasb[((size_t)ii*12 + col)*512 + jj] = acc[r];
    }
  }
}

// ---------------- per-residue attention ----------------
__global__ __launch_bounds__(512) void attn_kernel(
    const float* __restrict__ P, const float* __restrict__ qpg,
    const float* __restrict__ kT, const float* __restrict__ kpgT,
    const float* __restrict__ biasb, const float* __restrict__ z,
    const unsigned short* __restrict__ vcatT,
    const float* __restrict__ T, const float* __restrict__ gamma,
    short* __restrict__ cat)
{
  __shared__ float sc[16][516];                 // rows 12..15 garbage, discarded
  __shared__ float qrow[192], qpgrow[144], gsp[12], Ri[9], ti[3];
  __shared__ float obuf[192], opgbuf[288];
  int i = blockIdx.x, tid = threadIdx.x;

  if (tid < 192) qrow[tid] = P[(size_t)i*1152 + tid];
  { int t2 = tid - 192; if (t2 >= 0 && t2 < 144) qpgrow[t2] = qpg[(size_t)i*144 + t2]; }
  { int t3 = tid - 336; if (t3 >= 0 && t3 < 12) { float g = gamma[t3]; gsp[t3] = log1pf(__expf(g)); } }
  { int t4 = tid - 352; if (t4 >= 0 && t4 < 9) Ri[t4] = T[i*16 + (t4/3)*4 + (t4%3)]; }
  { int t5 = tid - 364; if (t5 >= 0 && t5 < 3) ti[t5] = T[i*16 + t5*4 + 3]; }
  __syncthreads();

  // P1: logits (biasb already scaled by wL)
  {
    const int j = tid;
    const float wL = 0.57735026918962576f;
    const float wC = 0.23570226039551584f;
    for (int h=0; h<12; ++h) {
      float dot = 0.f;
      #pragma unroll
      for (int c=0;c<16;++c) dot += qrow[h*16+c] * kT[(h*16+c)*512 + j];
      float d2 = 0.f;
      #pragma unroll
      for (int e=0;e<12;++e){ float d = qpgrow[h*12+e] - kpgT[(h*12+e)*512 + j]; d2 += d*d; }
      float b = biasb[((size_t)i*12 + h)*512 + j];
      sc[h][j] = wL*(dot*0.25f - 0.5f*gsp[h]*wC*d2) + b;
    }
  }
  __syncthreads();

  // P2: softmax per head (wave per head)
  {
    int w = tid >> 6, lane = tid & 63;
    for (int r=0; r<2; ++r) {
      int h = w + r*8;
      if (h < 12) {
        float v[8]; float m = -1e30f;
        #pragma unroll
        for (int u=0;u<8;++u){ v[u] = sc[h][lane + u*64]; m = fmaxf(m, v[u]); }
        #pragma unroll
        for (int s=32;s>0;s>>=1) m = fmaxf(m, __shfl_xor(m, s));
        float sum = 0.f;
        #pragma unroll
        for (int u=0;u<8;++u){ v[u] = __expf(v[u]-m); sum += v[u]; }
        #pragma unroll
        for (int s=32;s>0;s>>=1) sum += __shfl_xor(sum, s);
        float rinv = 1.f/sum;
        #pragma unroll
        for (int u=0;u<8;++u) sc[h][lane + u*64] = v[u]*rinv;
      }
    }
  }
  __syncthreads();

  // P3: o (192) and opg (288): one thread per output, over vcatT rows (bf16)
  if (tid < 480) {
    int d = tid;
    int h = (d < 192) ? (d >> 4) : ((d - 192) / 24);
    const unsigned short* vp = vcatT + (size_t)d*512;
    float s = 0.f;
    #pragma unroll 4
    for (int jc = 0; jc < 64; ++jc) {
      short8v vv = *(const short8v*)(vp + jc*8);
      #pragma unroll
      for (int e=0;e<8;++e) s += sc[h][jc*8+e] * bf2f((unsigned short)vv[e]);
    }
    if (d < 192) obuf[d] = s; else opgbuf[d-192] = s;
  }
  __syncthreads();

  // P4: o_pair = a @ z[i] via MFMA 16x16x32, one N-tile (16 z-cols) per wave
  {
    int w = tid >> 6, lane = tid & 63;
    int col = lane & 15, kg = lane >> 4;
    int zc0 = w * 16;
    const float* zb = z + (size_t)i * 65536;       // [512][128] f32
    f32x4 pacc = {0.f,0.f,0.f,0.f};
    for (int ks = 0; ks < 16; ++ks) {
      int j0 = ks*32 + kg*8;
      float4 a0 = *(const float4*)&sc[col][j0];
      float4 a1 = *(const float4*)&sc[col][j0 + 4];
      short8v af;
      af[0]=f2bf(a0.x); af[1]=f2bf(a0.y); af[2]=f2bf(a0.z); af[3]=f2bf(a0.w);
      af[4]=f2bf(a1.x); af[5]=f2bf(a1.y); af[6]=f2bf(a1.z); af[7]=f2bf(a1.w);
      short8v bfv;
      #pragma unroll
      for (int e=0;e<8;++e)
        bfv[e] = f2bf(zb[(size_t)(j0 + e)*128 + zc0 + col]);
      pacc = __builtin_amdgcn_mfma_f32_16x16x32_bf16(af, bfv, pacc, 0, 0, 0);
    }
    short* crow = cat + (size_t)i*2112;
    #pragma unroll
    for (int r=0;r<4;++r){
      int h = kg*4 + r;
      if (h < 12) crow[576 + h*128 + zc0 + col] = f2bf(pacc[r]);
    }
  }

  // P5: finalize o / op / norm parts of cat row (bf16)
  short* crow = cat + (size_t)i*2112;
  if (tid < 192) crow[tid] = f2bf(obuf[tid]);
  else if (tid < 288) {
    int idx = tid - 192;
    float d0 = opgbuf[idx*3+0]-ti[0], d1 = opgbuf[idx*3+1]-ti[1], d2v = opgbuf[idx*3+2]-ti[2];
    float o0 = Ri[0]*d0 + Ri[3]*d1 + Ri[6]*d2v;
    float o1 = Ri[1]*d0 + Ri[4]*d1 + Ri[7]*d2v;
    float o2 = Ri[2]*d0 + Ri[5]*d1 + Ri[8]*d2v;
    crow[192+idx*3+0] = f2bf(o0); crow[192+idx*3+1] = f2bf(o1); crow[192+idx*3+2] = f2bf(o2);
    crow[480+idx] = f2bf(sqrtf(o0*o0 + o1*o1 + o2*o2 + 1e-8f));
  }
}

// ---------------- launch ----------------
extern "C" void kernel_launch(void* const* d_in, const int* in_sizes, int n_in,
                              void* d_out, int out_size, void* d_ws, size_t ws_size,
                              hipStream_t stream) {
  const float* s     = (const float*)d_in[0];
  const float* z     = (const float*)d_in[1];
  const float* T     = (const float*)d_in[2];
  const float* w_q   = (const float*)d_in[3];
  const float* w_k   = (const float*)d_in[4];
  const float* w_v   = (const float*)d_in[5];
  const float* w_qp  = (const float*)d_in[6];
  const float* w_kp  = (const float*)d_in[7];
  const float* w_vp  = (const float*)d_in[8];
  const float* w_b   = (const float*)d_in[9];
  const float* gamma = (const float*)d_in[10];
  const float* w_out = (const float*)d_in[11];
  const float* b_out = (const float*)d_in[12];

  float* ws = (float*)d_ws;
  float* P      = ws;                        // 589824
  float* kT     = ws + 589824;               // 98304
  float* kpgT   = ws + 688128;               // 73728
  float* qpg    = ws + 761856;               // 73728
  float* biasb  = ws + 835584;               // 3145728
  short* s_bf   = (short*)(ws + 3981312);    // 196608 shorts
  short* WT     = (short*)(ws + 4079616);    // 442368 shorts
  short* w_outT = (short*)(ws + 4300800);    // 811008 shorts
  unsigned short* vcatT = (unsigned short*)(ws + 4706304); // 245760 shorts
  short* cat    = (short*)(ws + 4829184);    // 1081344 shorts

  cast_s_kernel<<<192, 256, 0, stream>>>(s, s_bf);
  transpose_w_kernel<<<dim3(5,6,6), 256, 0, stream>>>(w_q, w_k, w_v, w_qp, w_kp, w_vp, WT);
  transpose_wout_kernel<<<dim3(6,33), 256, 0, stream>>>(w_out, w_outT);
  gemm_bf16_kernel<<<dim3(9,4), 256, 0, stream>>>(s_bf, WT, P, nullptr, 512, 1152, 384);
  transform_kernel<<<64, 256, 0, stream>>>(P, T, kT, kpgT, qpg, vcatT);
  zpass_kernel<<<4096, 256, 0, stream>>>(z, w_b, biasb);
  attn_kernel<<<512, 512, 0, stream>>>(P, qpg, kT, kpgT, biasb, z, vcatT, T, gamma, cat);
  gemm_bf16_kernel<<<dim3(3,4), 256, 0, stream>>>(cat, w_outT, (float*)d_out, b_out, 512, 384, 2112);
}